// Round 3
// baseline (252.813 us; speedup 1.0000x reference)
//
#include <hip/hip_runtime.h>

// B=8, C=512, H=W=32, HW=1024, M=8192. scale = 1/sqrt(512).
// Pipeline: prep (x transpose->bf16, W pack->bf16) ; gemm_qk (bf16 MFMA -> fp8 q|k)
//           gemm_scores (MX-scaled fp8 MFMA K=128, fused per-tile row-max) ;
//           softmax ; gemm_out (bf16 MFMA with gating*xw + bias fused, transposed store)

typedef __attribute__((ext_vector_type(8))) short bf16x8;
typedef __attribute__((ext_vector_type(4))) float f32x4;
typedef __attribute__((ext_vector_type(4))) int i32x4;
typedef __attribute__((ext_vector_type(8))) int i32x8;

__device__ __forceinline__ unsigned short f2bf(float f) {
  unsigned u = __builtin_bit_cast(unsigned, f);
  u += 0x7FFFu + ((u >> 16) & 1u);
  return (unsigned short)(u >> 16);
}

// float -> OCP e4m3fn, RNE, saturate to 448.
__device__ __forceinline__ unsigned char f2e4m3(float x) {
  unsigned u = __builtin_bit_cast(unsigned, x);
  unsigned char s = (unsigned char)((u >> 24) & 0x80u);
  unsigned a = u & 0x7FFFFFFFu;
  if (a >= 0x43E00000u) return s | 0x7Eu;      // clamp to 448
  if (a < 0x3C800000u) {                        // below 2^-6: subnormal (quantum 2^-9)
    float q = __builtin_bit_cast(float, a) * 512.f;
    int m = (int)(q + 0.5f);
    return s | (unsigned char)m;
  }
  unsigned r = a + 0x7FFFFu + ((a >> 20) & 1u); // RNE at mantissa bit 20
  int e = (int)((r >> 23) & 0xFF) - 127;
  if (e > 8) return s | 0x7Eu;
  unsigned m3 = (r >> 20) & 0x7u;
  return s | (unsigned char)(((e + 7) << 3) | m3);
}

__device__ __forceinline__ void gload_lds16(const void* g, void* l) {
  __builtin_amdgcn_global_load_lds(
      (const __attribute__((address_space(1))) unsigned int*)g,
      (__attribute__((address_space(3))) unsigned int*)l, 16, 0, 0);
}

// ---------------------------------------------------------------------------
// prep: blocks [0,1024): transpose x [b][c][p] -> xt [b*1024+p][c] bf16
//       blocks [1024,1792): pack Wq|Wk|W6 -> wcat bf16 [1536][512]
__global__ __launch_bounds__(256) void prep(const float* __restrict__ x,
                                            const float* __restrict__ Wq,
                                            const float* __restrict__ Wk,
                                            const float* __restrict__ W6,
                                            short* __restrict__ xt,
                                            short* __restrict__ wcat) {
  const int bid = blockIdx.x, u = threadIdx.x;
  if (bid < 1024) {
    const int p0 = (bid & 15) * 64, c0 = ((bid >> 4) & 7) * 64, b = bid >> 7;
    __shared__ float t[64][65];
    {
      const int p4 = u & 15, cr = u >> 4;
      for (int cc = 0; cc < 4; ++cc) {
        const int c = cc * 16 + cr;
        const float4 v = *(const float4*)&x[((size_t)(b * 512 + c0 + c)) * 1024 + p0 + p4 * 4];
        t[p4 * 4 + 0][c] = v.x; t[p4 * 4 + 1][c] = v.y;
        t[p4 * 4 + 2][c] = v.z; t[p4 * 4 + 3][c] = v.w;
      }
    }
    __syncthreads();
    {
      const int c4 = u & 15, pr = u >> 4;
      for (int pp = 0; pp < 4; ++pp) {
        const int p = pp * 16 + pr;
        ushort4 o;
        o.x = f2bf(t[p][c4 * 4 + 0]); o.y = f2bf(t[p][c4 * 4 + 1]);
        o.z = f2bf(t[p][c4 * 4 + 2]); o.w = f2bf(t[p][c4 * 4 + 3]);
        *(ushort4*)&xt[((size_t)(b * 1024 + p0 + p)) * 512 + c0 + c4 * 4] = o;
      }
    }
  } else {
    const int i = (bid - 1024) * 256 + u;
    const int idx = i * 4;
    const float* src = (idx < 262144) ? Wq : (idx < 524288) ? Wk : W6;
    const float4 v = *(const float4*)&src[idx & 262143];
    ushort4 o;
    o.x = f2bf(v.x); o.y = f2bf(v.y); o.z = f2bf(v.z); o.w = f2bf(v.w);
    *(ushort4*)&wcat[idx] = o;
  }
}

// ---------------------------------------------------------------------------
// gemm_qk: [8192][1024] = xt @ wcat[0:1024]^T + bias -> fp8 qk8
// 128x128 tile, BK=32 (bf16), frag-ordered LDS
__global__ __launch_bounds__(256) void gemm_qk(const short* __restrict__ xt,
                                               const short* __restrict__ wcat,
                                               const float* __restrict__ bq,
                                               const float* __restrict__ bk,
                                               unsigned char* __restrict__ qk8) {
  __shared__ short lds_a[128 * 32];
  __shared__ short lds_b[128 * 32];
  const int tid = threadIdx.x, w = tid >> 6, lane = tid & 63;
  const int wr = w >> 1, wc = w & 1;
  const int quad = lane >> 4, lcol = lane & 15;
  const int skq = lane >> 4, srow = lane & 15;
  const int m0 = blockIdx.x * 128, n0 = blockIdx.y * 128;

  f32x4 acc[4][4];
#pragma unroll
  for (int i = 0; i < 4; ++i)
#pragma unroll
    for (int j = 0; j < 4; ++j)
#pragma unroll
      for (int r = 0; r < 4; ++r) acc[i][j][r] = 0.f;

  const short* Abase = xt + (size_t)(m0 + srow) * 512 + skq * 8;
  const short* Bbase = wcat + (size_t)(n0 + srow) * 512 + skq * 8;

  for (int kt = 0; kt < 16; ++kt) {
    const int kb = kt * 32;
    __syncthreads();
    gload_lds16(Abase + (size_t)(w * 16) * 512 + kb,       lds_a + w * 512);
    gload_lds16(Abase + (size_t)((4 + w) * 16) * 512 + kb, lds_a + (4 + w) * 512);
    gload_lds16(Bbase + (size_t)(w * 16) * 512 + kb,       lds_b + w * 512);
    gload_lds16(Bbase + (size_t)((4 + w) * 16) * 512 + kb, lds_b + (4 + w) * 512);
    __syncthreads();
    bf16x8 af[4], bf[4];
#pragma unroll
    for (int i = 0; i < 4; ++i) af[i] = *(const bf16x8*)&lds_a[(wr * 4 + i) * 512 + lane * 8];
#pragma unroll
    for (int j = 0; j < 4; ++j) bf[j] = *(const bf16x8*)&lds_b[(wc * 4 + j) * 512 + lane * 8];
#pragma unroll
    for (int i = 0; i < 4; ++i)
#pragma unroll
      for (int j = 0; j < 4; ++j)
        acc[i][j] = __builtin_amdgcn_mfma_f32_16x16x32_bf16(af[i], bf[j], acc[i][j], 0, 0, 0);
  }

  const float* bias = (blockIdx.y >= 4) ? bk : bq;
#pragma unroll
  for (int i = 0; i < 4; ++i)
#pragma unroll
    for (int j = 0; j < 4; ++j) {
      const int row = m0 + wr * 64 + i * 16 + quad * 4;
      const int col = n0 + wc * 64 + j * 16 + lcol;
      const float bv = bias[col & 511];
#pragma unroll
      for (int r = 0; r < 4; ++r)
        qk8[(size_t)(row + r) * 1024 + col] = f2e4m3(acc[i][j][r] + bv);
    }
}

// ---------------------------------------------------------------------------
// gemm_scores: q @ k^T via MX-scaled fp8 MFMA (K=128, scales = 1.0),
// fused per-row max over each 128-col tile.
// LDS layout per matrix: 8 groups (16 rows) x 2048 B; group = two 1 KB halves
// (k-half h in [0,64),[64,128)), each stored lane-ordered: half + lane*16.
// Frag for acc i: lo = b128 @ (wr*4+i)*2048 + lane*16, hi = lo + 1024.
// Same k-slot permutation for A and B -> exact dot product; scale=1 is
// permutation-immune.
__global__ __launch_bounds__(256) void gemm_scores(const unsigned char* __restrict__ qk8,
                                                   float* __restrict__ wsmx) {
  __shared__ unsigned char lds_a[16384];
  __shared__ unsigned char lds_b[16384];
  __shared__ float partial[128][2];
  const int tid = threadIdx.x, w = tid >> 6, lane = tid & 63;
  const int wr = w >> 1, wc = w & 1;
  const int quad = lane >> 4, lcol = lane & 15;
  const int srow = lane & 15;          // staging row within 16-group
  const int skb = (lane >> 4) * 16;    // staging k-byte offset within 64-B half
  const int m0 = blockIdx.x * 128, n0 = blockIdx.y * 128;

  f32x4 acc[4][4];
#pragma unroll
  for (int i = 0; i < 4; ++i)
#pragma unroll
    for (int j = 0; j < 4; ++j)
#pragma unroll
      for (int r = 0; r < 4; ++r) acc[i][j][r] = 0.f;

  // wave w stages groups 2w and 2w+1 (rows 32w..32w+31) of both A and B
  const unsigned char* Abase = qk8 + (size_t)(m0 + w * 32 + srow) * 1024 + skb;
  const unsigned char* Bbase = qk8 + (size_t)(n0 + w * 32 + srow) * 1024 + 512 + skb;
  unsigned char* la0 = lds_a + (w * 2) * 2048;
  unsigned char* lb0 = lds_b + (w * 2) * 2048;

  for (int kt = 0; kt < 4; ++kt) {
    const int kb = kt * 128;
    __syncthreads();
    gload_lds16(Abase + kb,                       la0);         // g=2w,   h=0
    gload_lds16(Abase + kb + 64,                  la0 + 1024);  // g=2w,   h=1
    gload_lds16(Abase + (size_t)16 * 1024 + kb,      la0 + 2048);  // g=2w+1, h=0
    gload_lds16(Abase + (size_t)16 * 1024 + kb + 64, la0 + 3072);  // g=2w+1, h=1
    gload_lds16(Bbase + kb,                       lb0);
    gload_lds16(Bbase + kb + 64,                  lb0 + 1024);
    gload_lds16(Bbase + (size_t)16 * 1024 + kb,      lb0 + 2048);
    gload_lds16(Bbase + (size_t)16 * 1024 + kb + 64, lb0 + 3072);
    __syncthreads();
    i32x8 af[4], bf[4];
#pragma unroll
    for (int i = 0; i < 4; ++i) {
      const unsigned char* pa = lds_a + (wr * 4 + i) * 2048 + lane * 16;
      const i32x4 lo = *(const i32x4*)pa;
      const i32x4 hi = *(const i32x4*)(pa + 1024);
      af[i] = __builtin_shufflevector(lo, hi, 0, 1, 2, 3, 4, 5, 6, 7);
    }
#pragma unroll
    for (int j = 0; j < 4; ++j) {
      const unsigned char* pb = lds_b + (wc * 4 + j) * 2048 + lane * 16;
      const i32x4 lo = *(const i32x4*)pb;
      const i32x4 hi = *(const i32x4*)(pb + 1024);
      bf[j] = __builtin_shufflevector(lo, hi, 0, 1, 2, 3, 4, 5, 6, 7);
    }
#pragma unroll
    for (int i = 0; i < 4; ++i)
#pragma unroll
      for (int j = 0; j < 4; ++j)
        acc[i][j] = __builtin_amdgcn_mfma_scale_f32_16x16x128_f8f6f4(
            af[i], bf[j], acc[i][j], 0, 0, 0, 127, 0, 127);
  }

#pragma unroll
  for (int i = 0; i < 4; ++i) {
#pragma unroll
    for (int r = 0; r < 4; ++r) {
      float v = fmaxf(fmaxf(acc[i][0][r], acc[i][1][r]),
                      fmaxf(acc[i][2][r], acc[i][3][r]));
#pragma unroll
      for (int off = 1; off < 16; off <<= 1) v = fmaxf(v, __shfl_xor(v, off));
      if (lcol == 0) partial[wr * 64 + i * 16 + quad * 4 + r][wc] = v;
    }
  }
  __syncthreads();
  if (tid < 128)
    wsmx[(size_t)blockIdx.y * 8192 + m0 + tid] = fmaxf(partial[tid][0], partial[tid][1]);
}

// ---------------------------------------------------------------------------
// softmax_xw: logit[m] = scale * mean_img( max over img's 8 col-tiles ); softmax per image
__global__ __launch_bounds__(1024) void softmax_xw(const float* __restrict__ wsmx,
                                                   float* __restrict__ xw) {
  const int b = blockIdx.x, p = threadIdx.x;
  const int m = b * 1024 + p;
  float s = 0.f;
#pragma unroll
  for (int img = 0; img < 8; ++img) {
    float mx = -1e30f;
#pragma unroll
    for (int t = 0; t < 8; ++t) mx = fmaxf(mx, wsmx[(size_t)(img * 8 + t) * 8192 + m]);
    s += mx;
  }
  const float logit = s * 0.005524271728019903f;  // (1/8) * (1/sqrt(512))
  __shared__ float red[16];
  float v = logit;
#pragma unroll
  for (int off = 32; off >= 1; off >>= 1) v = fmaxf(v, __shfl_xor(v, off));
  if ((p & 63) == 0) red[p >> 6] = v;
  __syncthreads();
  float bmax = red[0];
#pragma unroll
  for (int t = 1; t < 16; ++t) bmax = fmaxf(bmax, red[t]);
  const float e = expf(logit - bmax);
  float sv = e;
#pragma unroll
  for (int off = 32; off >= 1; off >>= 1) sv += __shfl_xor(sv, off);
  __syncthreads();
  if ((p & 63) == 0) red[p >> 6] = sv;
  __syncthreads();
  float bsum = 0.f;
#pragma unroll
  for (int t = 0; t < 16; ++t) bsum += red[t];
  xw[m] = e / bsum;
}

// ---------------------------------------------------------------------------
// gemm_out: out[b][co][p] = (xt @ W6^T)[m][co] * xw[m] + b6[co], m = b*1024+p.
__global__ __launch_bounds__(256) void gemm_out(const short* __restrict__ xt,
                                                const short* __restrict__ wcat,
                                                const float* __restrict__ xw,
                                                const float* __restrict__ b6,
                                                float* __restrict__ out) {
  __shared__ short lds_a[128 * 32];
  __shared__ short lds_b[128 * 32];
  const int tid = threadIdx.x, w = tid >> 6, lane = tid & 63;
  const int wr = w >> 1, wc = w & 1;
  const int quad = lane >> 4, lcol = lane & 15;
  const int skq = lane >> 4, srow = lane & 15;
  const int m0 = blockIdx.x * 128, n0 = blockIdx.y * 128;

  f32x4 acc[4][4];
#pragma unroll
  for (int i = 0; i < 4; ++i)
#pragma unroll
    for (int j = 0; j < 4; ++j)
#pragma unroll
      for (int r = 0; r < 4; ++r) acc[i][j][r] = 0.f;

  const short* Abase = xt + (size_t)(m0 + srow) * 512 + skq * 8;
  const short* Bbase = wcat + (size_t)(1024 + n0 + srow) * 512 + skq * 8;

  for (int kt = 0; kt < 16; ++kt) {
    const int kb = kt * 32;
    __syncthreads();
    gload_lds16(Abase + (size_t)(w * 16) * 512 + kb,       lds_a + w * 512);
    gload_lds16(Abase + (size_t)((4 + w) * 16) * 512 + kb, lds_a + (4 + w) * 512);
    gload_lds16(Bbase + (size_t)(w * 16) * 512 + kb,       lds_b + w * 512);
    gload_lds16(Bbase + (size_t)((4 + w) * 16) * 512 + kb, lds_b + (4 + w) * 512);
    __syncthreads();
    bf16x8 af[4], bf[4];
#pragma unroll
    for (int i = 0; i < 4; ++i) af[i] = *(const bf16x8*)&lds_a[(wr * 4 + i) * 512 + lane * 8];
#pragma unroll
    for (int j = 0; j < 4; ++j) bf[j] = *(const bf16x8*)&lds_b[(wc * 4 + j) * 512 + lane * 8];
#pragma unroll
    for (int i = 0; i < 4; ++i)
#pragma unroll
      for (int j = 0; j < 4; ++j)
        acc[i][j] = __builtin_amdgcn_mfma_f32_16x16x32_bf16(af[i], bf[j], acc[i][j], 0, 0, 0);
  }

#pragma unroll
  for (int i = 0; i < 4; ++i) {
    const int mbase = m0 + wr * 64 + i * 16 + quad * 4;
    const int b = mbase >> 10, p = mbase & 1023;
    const float4 wv = *(const float4*)&xw[mbase];
#pragma unroll
    for (int j = 0; j < 4; ++j) {
      const int col = n0 + wc * 64 + j * 16 + lcol;
      const float bias = b6[col];
      float4 o;
      o.x = acc[i][j][0] * wv.x + bias;
      o.y = acc[i][j][1] * wv.y + bias;
      o.z = acc[i][j][2] * wv.z + bias;
      o.w = acc[i][j][3] * wv.w + bias;
      *(float4*)&out[((size_t)(b * 512 + col)) * 1024 + p] = o;
    }
  }
}

// ---------------------------------------------------------------------------
extern "C" void kernel_launch(void* const* d_in, const int* in_sizes, int n_in,
                              void* d_out, int out_size, void* d_ws, size_t ws_size,
                              hipStream_t stream) {
  const float* x  = (const float*)d_in[0];
  const float* Wq = (const float*)d_in[1];
  const float* bq = (const float*)d_in[2];
  const float* Wk = (const float*)d_in[3];
  const float* bk = (const float*)d_in[4];
  const float* W6 = (const float*)d_in[5];
  const float* b6 = (const float*)d_in[6];
  float* out = (float*)d_out;

  char* ws = (char*)d_ws;
  short* xt          = (short*)(ws + 0);          //  8 MB  bf16 [8192][512]
  short* wcat        = (short*)(ws + 8388608);    //  1.5MB bf16 [1536][512]
  unsigned char* qk8 = (unsigned char*)(ws + 10485760);  // 8 MB fp8 [8192][1024]
  float* wsmx        = (float*)(ws + 18874368);   //  2 MB  fp32 [64][8192]
  float* xw          = (float*)(ws + 20971520);   // 32 KB  fp32 [8192]

  prep<<<1792, 256, 0, stream>>>(x, Wq, Wk, W6, xt, wcat);
  gemm_qk<<<dim3(64, 8), 256, 0, stream>>>(xt, wcat, bq, bk, qk8);
  gemm_scores<<<dim3(64, 64), 256, 0, stream>>>(qk8, wsmx);
  softmax_xw<<<8, 1024, 0, stream>>>(wsmx, xw);
  gemm_out<<<dim3(64, 4), 256, 0, stream>>>(xt, wcat, xw, b6, out);
}

// Round 4
// 194.471 us; speedup vs baseline: 1.3000x; 1.3000x over previous
//
#include <hip/hip_runtime.h>

// B=8, C=512, H=W=32, HW=1024, M=8192. scale = 1/sqrt(512).
// prep (x transpose->bf16, W pack->bf16) ; gemm_qk (bf16 MFMA, BK=64 -> fp8 q|k)
// gemm_scores (non-scaled fp8 MFMA, fused per-tile row-max)  [Round-2 verbatim]
// softmax ; gemm_out (64x64 tiles, 1024 blocks, gating*xw + bias fused, transposed store)

typedef __attribute__((ext_vector_type(8))) short bf16x8;
typedef __attribute__((ext_vector_type(4))) float f32x4;
typedef __attribute__((ext_vector_type(2))) long long i64x2;

__device__ __forceinline__ unsigned short f2bf(float f) {
  unsigned u = __builtin_bit_cast(unsigned, f);
  u += 0x7FFFu + ((u >> 16) & 1u);
  return (unsigned short)(u >> 16);
}

// float -> OCP e4m3fn, RNE, saturate to 448.
__device__ __forceinline__ unsigned char f2e4m3(float x) {
  unsigned u = __builtin_bit_cast(unsigned, x);
  unsigned char s = (unsigned char)((u >> 24) & 0x80u);
  unsigned a = u & 0x7FFFFFFFu;
  if (a >= 0x43E00000u) return s | 0x7Eu;      // clamp to 448
  if (a < 0x3C800000u) {                        // below 2^-6: subnormal (quantum 2^-9)
    float q = __builtin_bit_cast(float, a) * 512.f;
    int m = (int)(q + 0.5f);
    return s | (unsigned char)m;
  }
  unsigned r = a + 0x7FFFFu + ((a >> 20) & 1u); // RNE at mantissa bit 20
  int e = (int)((r >> 23) & 0xFF) - 127;
  if (e > 8) return s | 0x7Eu;
  unsigned m3 = (r >> 20) & 0x7u;
  return s | (unsigned char)(((e + 7) << 3) | m3);
}

__device__ __forceinline__ void gload_lds16(const void* g, void* l) {
  __builtin_amdgcn_global_load_lds(
      (const __attribute__((address_space(1))) unsigned int*)g,
      (__attribute__((address_space(3))) unsigned int*)l, 16, 0, 0);
}

// ---------------------------------------------------------------------------
// prep: blocks [0,1024): transpose x [b][c][p] -> xt [b*1024+p][c] bf16
//       blocks [1024,1792): pack Wq|Wk|W6 -> wcat bf16 [1536][512]
__global__ __launch_bounds__(256) void prep(const float* __restrict__ x,
                                            const float* __restrict__ Wq,
                                            const float* __restrict__ Wk,
                                            const float* __restrict__ W6,
                                            short* __restrict__ xt,
                                            short* __restrict__ wcat) {
  const int bid = blockIdx.x, u = threadIdx.x;
  if (bid < 1024) {
    const int p0 = (bid & 15) * 64, c0 = ((bid >> 4) & 7) * 64, b = bid >> 7;
    __shared__ float t[64][65];
    {
      const int p4 = u & 15, cr = u >> 4;
      for (int cc = 0; cc < 4; ++cc) {
        const int c = cc * 16 + cr;
        const float4 v = *(const float4*)&x[((size_t)(b * 512 + c0 + c)) * 1024 + p0 + p4 * 4];
        t[p4 * 4 + 0][c] = v.x; t[p4 * 4 + 1][c] = v.y;
        t[p4 * 4 + 2][c] = v.z; t[p4 * 4 + 3][c] = v.w;
      }
    }
    __syncthreads();
    {
      const int c4 = u & 15, pr = u >> 4;
      for (int pp = 0; pp < 4; ++pp) {
        const int p = pp * 16 + pr;
        ushort4 o;
        o.x = f2bf(t[p][c4 * 4 + 0]); o.y = f2bf(t[p][c4 * 4 + 1]);
        o.z = f2bf(t[p][c4 * 4 + 2]); o.w = f2bf(t[p][c4 * 4 + 3]);
        *(ushort4*)&xt[((size_t)(b * 1024 + p0 + p)) * 512 + c0 + c4 * 4] = o;
      }
    }
  } else {
    const int i = (bid - 1024) * 256 + u;
    const int idx = i * 4;
    const float* src = (idx < 262144) ? Wq : (idx < 524288) ? Wk : W6;
    const float4 v = *(const float4*)&src[idx & 262143];
    ushort4 o;
    o.x = f2bf(v.x); o.y = f2bf(v.y); o.z = f2bf(v.z); o.w = f2bf(v.w);
    *(ushort4*)&wcat[idx] = o;
  }
}

// ---------------------------------------------------------------------------
// gemm_qk: [8192][1024] = xt @ wcat[0:1024]^T + bias -> fp8 qk8
// 128x128 tile, BK=64 bf16 elems (8 kt iterations, halved barrier count).
// LDS layout per matrix: 8 groups (16 rows) x 2048 B; group = two 1 KB halves
// (k-elems [0,32) / [32,64)), each half lane-ordered: g*2048 + h*1024 + lane*16.
__global__ __launch_bounds__(256) void gemm_qk(const short* __restrict__ xt,
                                               const short* __restrict__ wcat,
                                               const float* __restrict__ bq,
                                               const float* __restrict__ bk,
                                               unsigned char* __restrict__ qk8) {
  __shared__ short lds_a[128 * 64];  // 16 KB
  __shared__ short lds_b[128 * 64];
  const int tid = threadIdx.x, w = tid >> 6, lane = tid & 63;
  const int wr = w >> 1, wc = w & 1;
  const int quad = lane >> 4, lcol = lane & 15;
  const int srow = lane & 15, skq = lane >> 4;
  const int m0 = blockIdx.x * 128, n0 = blockIdx.y * 128;

  f32x4 acc[4][4];
#pragma unroll
  for (int i = 0; i < 4; ++i)
#pragma unroll
    for (int j = 0; j < 4; ++j)
#pragma unroll
      for (int r = 0; r < 4; ++r) acc[i][j][r] = 0.f;

  // wave w stages groups {w, w+4} of both A and B (each group: 2 glds halves)
  const short* Abase = xt + (size_t)(m0 + srow) * 512 + skq * 8;
  const short* Bbase = wcat + (size_t)(n0 + srow) * 512 + skq * 8;

  for (int kt = 0; kt < 8; ++kt) {
    const int kb = kt * 64;
    __syncthreads();
#pragma unroll
    for (int gg = 0; gg < 2; ++gg) {
      const int g = w + gg * 4;
      gload_lds16(Abase + (size_t)(g * 16) * 512 + kb,      lds_a + g * 1024);
      gload_lds16(Abase + (size_t)(g * 16) * 512 + kb + 32, lds_a + g * 1024 + 512);
      gload_lds16(Bbase + (size_t)(g * 16) * 512 + kb,      lds_b + g * 1024);
      gload_lds16(Bbase + (size_t)(g * 16) * 512 + kb + 32, lds_b + g * 1024 + 512);
    }
    __syncthreads();
#pragma unroll
    for (int h = 0; h < 2; ++h) {
      bf16x8 af[4], bf[4];
#pragma unroll
      for (int i = 0; i < 4; ++i)
        af[i] = *(const bf16x8*)&lds_a[(wr * 4 + i) * 1024 + h * 512 + lane * 8];
#pragma unroll
      for (int j = 0; j < 4; ++j)
        bf[j] = *(const bf16x8*)&lds_b[(wc * 4 + j) * 1024 + h * 512 + lane * 8];
#pragma unroll
      for (int i = 0; i < 4; ++i)
#pragma unroll
        for (int j = 0; j < 4; ++j)
          acc[i][j] = __builtin_amdgcn_mfma_f32_16x16x32_bf16(af[i], bf[j], acc[i][j], 0, 0, 0);
    }
  }

  const float* bias = (blockIdx.y >= 4) ? bk : bq;
#pragma unroll
  for (int i = 0; i < 4; ++i)
#pragma unroll
    for (int j = 0; j < 4; ++j) {
      const int row = m0 + wr * 64 + i * 16 + quad * 4;
      const int col = n0 + wc * 64 + j * 16 + lcol;
      const float bv = bias[col & 511];
#pragma unroll
      for (int r = 0; r < 4; ++r)
        qk8[(size_t)(row + r) * 1024 + col] = f2e4m3(acc[i][j][r] + bv);
    }
}

// ---------------------------------------------------------------------------
// gemm_scores: q @ k^T (fp8 MFMA), fused per-row max over each 128-col tile.
// [Round-2 verbatim: 75.6 us, 909 TF, 0 bank conflicts]
__global__ __launch_bounds__(256) void gemm_scores(const unsigned char* __restrict__ qk8,
                                                   float* __restrict__ wsmx) {
  __shared__ unsigned char lds_a[8192];
  __shared__ unsigned char lds_b[8192];
  __shared__ float partial[128][2];
  const int tid = threadIdx.x, w = tid >> 6, lane = tid & 63;
  const int wr = w >> 1, wc = w & 1;
  const int quad = lane >> 4, lcol = lane & 15;
  const int skq = lane >> 4, srow = lane & 15;
  const int m0 = blockIdx.x * 128, n0 = blockIdx.y * 128;

  f32x4 acc[4][4];
#pragma unroll
  for (int i = 0; i < 4; ++i)
#pragma unroll
    for (int j = 0; j < 4; ++j)
#pragma unroll
      for (int r = 0; r < 4; ++r) acc[i][j][r] = 0.f;

  const unsigned char* Abase = qk8 + (size_t)(m0 + srow) * 1024 + skq * 16;
  const unsigned char* Bbase = qk8 + (size_t)(n0 + srow) * 1024 + 512 + skq * 16;

  for (int kt = 0; kt < 8; ++kt) {
    const int kb = kt * 64;
    __syncthreads();
    gload_lds16(Abase + (size_t)(w * 16) * 1024 + kb,       lds_a + w * 1024);
    gload_lds16(Abase + (size_t)((4 + w) * 16) * 1024 + kb, lds_a + (4 + w) * 1024);
    gload_lds16(Bbase + (size_t)(w * 16) * 1024 + kb,       lds_b + w * 1024);
    gload_lds16(Bbase + (size_t)((4 + w) * 16) * 1024 + kb, lds_b + (4 + w) * 1024);
    __syncthreads();
    i64x2 af[4], bf[4];
#pragma unroll
    for (int i = 0; i < 4; ++i) af[i] = *(const i64x2*)&lds_a[(wr * 4 + i) * 1024 + lane * 16];
#pragma unroll
    for (int j = 0; j < 4; ++j) bf[j] = *(const i64x2*)&lds_b[(wc * 4 + j) * 1024 + lane * 16];
#pragma unroll
    for (int i = 0; i < 4; ++i)
#pragma unroll
      for (int j = 0; j < 4; ++j) {
        acc[i][j] = __builtin_amdgcn_mfma_f32_16x16x32_fp8_fp8(af[i].x, bf[j].x, acc[i][j], 0, 0, 0);
        acc[i][j] = __builtin_amdgcn_mfma_f32_16x16x32_fp8_fp8(af[i].y, bf[j].y, acc[i][j], 0, 0, 0);
      }
  }

#pragma unroll
  for (int i = 0; i < 4; ++i) {
#pragma unroll
    for (int r = 0; r < 4; ++r) {
      float v = fmaxf(fmaxf(acc[i][0][r], acc[i][1][r]),
                      fmaxf(acc[i][2][r], acc[i][3][r]));
#pragma unroll
      for (int off = 1; off < 16; off <<= 1) v = fmaxf(v, __shfl_xor(v, off));
      if (lcol == 0) partial[wr * 64 + i * 16 + quad * 4 + r][wc] = v;
    }
  }
  __syncthreads();
  if (tid < 128)
    wsmx[(size_t)blockIdx.y * 8192 + m0 + tid] = fmaxf(partial[tid][0], partial[tid][1]);
}

// ---------------------------------------------------------------------------
// softmax_xw: logit[m] = scale * mean_img( max over img's 8 col-tiles ); softmax per image
__global__ __launch_bounds__(1024) void softmax_xw(const float* __restrict__ wsmx,
                                                   float* __restrict__ xw) {
  const int b = blockIdx.x, p = threadIdx.x;
  const int m = b * 1024 + p;
  float s = 0.f;
#pragma unroll
  for (int img = 0; img < 8; ++img) {
    float mx = -1e30f;
#pragma unroll
    for (int t = 0; t < 8; ++t) mx = fmaxf(mx, wsmx[(size_t)(img * 8 + t) * 8192 + m]);
    s += mx;
  }
  const float logit = s * 0.005524271728019903f;  // (1/8) * (1/sqrt(512))
  __shared__ float red[16];
  float v = logit;
#pragma unroll
  for (int off = 32; off >= 1; off >>= 1) v = fmaxf(v, __shfl_xor(v, off));
  if ((p & 63) == 0) red[p >> 6] = v;
  __syncthreads();
  float bmax = red[0];
#pragma unroll
  for (int t = 1; t < 16; ++t) bmax = fmaxf(bmax, red[t]);
  const float e = expf(logit - bmax);
  float sv = e;
#pragma unroll
  for (int off = 32; off >= 1; off >>= 1) sv += __shfl_xor(sv, off);
  __syncthreads();
  if ((p & 63) == 0) red[p >> 6] = sv;
  __syncthreads();
  float bsum = 0.f;
#pragma unroll
  for (int t = 0; t < 16; ++t) bsum += red[t];
  xw[m] = e / bsum;
}

// ---------------------------------------------------------------------------
// gemm_out: out[b][co][p] = (xt @ W6^T)[m][co] * xw[m] + b6[co], m = b*1024+p.
// 64x64 tiles, grid (128,8) = 1024 blocks (4/CU), BK=64, 8 kt iterations.
// Wave w: rows wr*32..+32, cols wc*32..+32 (wr=w>>1, wc=w&1): acc[2][2].
__global__ __launch_bounds__(256) void gemm_out(const short* __restrict__ xt,
                                                const short* __restrict__ wcat,
                                                const float* __restrict__ xw,
                                                const float* __restrict__ b6,
                                                float* __restrict__ out) {
  __shared__ short lds_a[64 * 64];  // 8 KB
  __shared__ short lds_b[64 * 64];
  const int tid = threadIdx.x, w = tid >> 6, lane = tid & 63;
  const int wr = w >> 1, wc = w & 1;
  const int quad = lane >> 4, lcol = lane & 15;
  const int srow = lane & 15, skq = lane >> 4;
  const int m0 = blockIdx.x * 64, n0 = blockIdx.y * 64;

  f32x4 acc[2][2];
#pragma unroll
  for (int i = 0; i < 2; ++i)
#pragma unroll
    for (int j = 0; j < 2; ++j)
#pragma unroll
      for (int r = 0; r < 4; ++r) acc[i][j][r] = 0.f;

  // wave w stages group w (16 rows) of both A and B
  const short* Abase = xt + (size_t)(m0 + w * 16 + srow) * 512 + skq * 8;
  const short* Bbase = wcat + (size_t)(1024 + n0 + w * 16 + srow) * 512 + skq * 8;

  for (int kt = 0; kt < 8; ++kt) {
    const int kb = kt * 64;
    __syncthreads();
    gload_lds16(Abase + kb,      lds_a + w * 1024);
    gload_lds16(Abase + kb + 32, lds_a + w * 1024 + 512);
    gload_lds16(Bbase + kb,      lds_b + w * 1024);
    gload_lds16(Bbase + kb + 32, lds_b + w * 1024 + 512);
    __syncthreads();
#pragma unroll
    for (int h = 0; h < 2; ++h) {
      bf16x8 af[2], bf[2];
#pragma unroll
      for (int i = 0; i < 2; ++i)
        af[i] = *(const bf16x8*)&lds_a[(wr * 2 + i) * 1024 + h * 512 + lane * 8];
#pragma unroll
      for (int j = 0; j < 2; ++j)
        bf[j] = *(const bf16x8*)&lds_b[(wc * 2 + j) * 1024 + h * 512 + lane * 8];
#pragma unroll
      for (int i = 0; i < 2; ++i)
#pragma unroll
        for (int j = 0; j < 2; ++j)
          acc[i][j] = __builtin_amdgcn_mfma_f32_16x16x32_bf16(af[i], bf[j], acc[i][j], 0, 0, 0);
    }
  }

#pragma unroll
  for (int i = 0; i < 2; ++i) {
    const int mbase = m0 + wr * 32 + i * 16 + quad * 4;
    const int b = mbase >> 10, p = mbase & 1023;
    const float4 wv = *(const float4*)&xw[mbase];
#pragma unroll
    for (int j = 0; j < 2; ++j) {
      const int col = n0 + wc * 32 + j * 16 + lcol;
      const float bias = b6[col];
      float4 o;
      o.x = acc[i][j][0] * wv.x + bias;
      o.y = acc[i][j][1] * wv.y + bias;
      o.z = acc[i][j][2] * wv.z + bias;
      o.w = acc[i][j][3] * wv.w + bias;
      *(float4*)&out[((size_t)(b * 512 + col)) * 1024 + p] = o;
    }
  }
}

// ---------------------------------------------------------------------------
extern "C" void kernel_launch(void* const* d_in, const int* in_sizes, int n_in,
                              void* d_out, int out_size, void* d_ws, size_t ws_size,
                              hipStream_t stream) {
  const float* x  = (const float*)d_in[0];
  const float* Wq = (const float*)d_in[1];
  const float* bq = (const float*)d_in[2];
  const float* Wk = (const float*)d_in[3];
  const float* bk = (const float*)d_in[4];
  const float* W6 = (const float*)d_in[5];
  const float* b6 = (const float*)d_in[6];
  float* out = (float*)d_out;

  char* ws = (char*)d_ws;
  short* xt          = (short*)(ws + 0);          //  8 MB  bf16 [8192][512]
  short* wcat        = (short*)(ws + 8388608);    //  1.5MB bf16 [1536][512]
  unsigned char* qk8 = (unsigned char*)(ws + 10485760);  // 8 MB fp8 [8192][1024]
  float* wsmx        = (float*)(ws + 18874368);   //  2 MB  fp32 [64][8192]
  float* xw          = (float*)(ws + 20971520);   // 32 KB  fp32 [8192]

  prep<<<1792, 256, 0, stream>>>(x, Wq, Wk, W6, xt, wcat);
  gemm_qk<<<dim3(64, 8), 256, 0, stream>>>(xt, wcat, bq, bk, qk8);
  gemm_scores<<<dim3(64, 64), 256, 0, stream>>>(qk8, wsmx);
  softmax_xw<<<8, 1024, 0, stream>>>(wsmx, xw);
  gemm_out<<<dim3(128, 8), 256, 0, stream>>>(xt, wcat, xw, b6, out);
}

// Round 5
// 191.637 us; speedup vs baseline: 1.3192x; 1.0148x over previous
//
#include <hip/hip_runtime.h>

// B=8, C=512, H=W=32, HW=1024, M=8192. scale = 1/sqrt(512).
// prep (x transpose->bf16, W pack->bf16) ; gemm_qk (bf16 MFMA, BK=64 -> fp8 q|k)
// gemm_scores (fp8 MFMA, barrier-light: A streamed per-lane, B in LDS 2 half-K
//              stages, wave-exclusive 32x128 tiles, fused per-tile row-max)
// softmax ; gemm_out (64x64 tiles, gating*xw + bias fused, transposed store)

typedef __attribute__((ext_vector_type(8))) short bf16x8;
typedef __attribute__((ext_vector_type(4))) float f32x4;
typedef __attribute__((ext_vector_type(2))) long long i64x2;

__device__ __forceinline__ unsigned short f2bf(float f) {
  unsigned u = __builtin_bit_cast(unsigned, f);
  u += 0x7FFFu + ((u >> 16) & 1u);
  return (unsigned short)(u >> 16);
}

// float -> OCP e4m3fn, RNE, saturate to 448.
__device__ __forceinline__ unsigned char f2e4m3(float x) {
  unsigned u = __builtin_bit_cast(unsigned, x);
  unsigned char s = (unsigned char)((u >> 24) & 0x80u);
  unsigned a = u & 0x7FFFFFFFu;
  if (a >= 0x43E00000u) return s | 0x7Eu;      // clamp to 448
  if (a < 0x3C800000u) {                        // below 2^-6: subnormal (quantum 2^-9)
    float q = __builtin_bit_cast(float, a) * 512.f;
    int m = (int)(q + 0.5f);
    return s | (unsigned char)m;
  }
  unsigned r = a + 0x7FFFFu + ((a >> 20) & 1u); // RNE at mantissa bit 20
  int e = (int)((r >> 23) & 0xFF) - 127;
  if (e > 8) return s | 0x7Eu;
  unsigned m3 = (r >> 20) & 0x7u;
  return s | (unsigned char)(((e + 7) << 3) | m3);
}

__device__ __forceinline__ void gload_lds16(const void* g, void* l) {
  __builtin_amdgcn_global_load_lds(
      (const __attribute__((address_space(1))) unsigned int*)g,
      (__attribute__((address_space(3))) unsigned int*)l, 16, 0, 0);
}

// ---------------------------------------------------------------------------
// prep: blocks [0,1024): transpose x [b][c][p] -> xt [b*1024+p][c] bf16
//       blocks [1024,1792): pack Wq|Wk|W6 -> wcat bf16 [1536][512]
__global__ __launch_bounds__(256) void prep(const float* __restrict__ x,
                                            const float* __restrict__ Wq,
                                            const float* __restrict__ Wk,
                                            const float* __restrict__ W6,
                                            short* __restrict__ xt,
                                            short* __restrict__ wcat) {
  const int bid = blockIdx.x, u = threadIdx.x;
  if (bid < 1024) {
    const int p0 = (bid & 15) * 64, c0 = ((bid >> 4) & 7) * 64, b = bid >> 7;
    __shared__ float t[64][65];
    {
      const int p4 = u & 15, cr = u >> 4;
      for (int cc = 0; cc < 4; ++cc) {
        const int c = cc * 16 + cr;
        const float4 v = *(const float4*)&x[((size_t)(b * 512 + c0 + c)) * 1024 + p0 + p4 * 4];
        t[p4 * 4 + 0][c] = v.x; t[p4 * 4 + 1][c] = v.y;
        t[p4 * 4 + 2][c] = v.z; t[p4 * 4 + 3][c] = v.w;
      }
    }
    __syncthreads();
    {
      const int c4 = u & 15, pr = u >> 4;
      for (int pp = 0; pp < 4; ++pp) {
        const int p = pp * 16 + pr;
        ushort4 o;
        o.x = f2bf(t[p][c4 * 4 + 0]); o.y = f2bf(t[p][c4 * 4 + 1]);
        o.z = f2bf(t[p][c4 * 4 + 2]); o.w = f2bf(t[p][c4 * 4 + 3]);
        *(ushort4*)&xt[((size_t)(b * 1024 + p0 + p)) * 512 + c0 + c4 * 4] = o;
      }
    }
  } else {
    const int i = (bid - 1024) * 256 + u;
    const int idx = i * 4;
    const float* src = (idx < 262144) ? Wq : (idx < 524288) ? Wk : W6;
    const float4 v = *(const float4*)&src[idx & 262143];
    ushort4 o;
    o.x = f2bf(v.x); o.y = f2bf(v.y); o.z = f2bf(v.z); o.w = f2bf(v.w);
    *(ushort4*)&wcat[idx] = o;
  }
}

// ---------------------------------------------------------------------------
// gemm_qk: [8192][1024] = xt @ wcat[0:1024]^T + bias -> fp8 qk8
// 128x128 tile, BK=64 bf16 elems, frag-ordered LDS (round-4 structure)
__global__ __launch_bounds__(256) void gemm_qk(const short* __restrict__ xt,
                                               const short* __restrict__ wcat,
                                               const float* __restrict__ bq,
                                               const float* __restrict__ bk,
                                               unsigned char* __restrict__ qk8) {
  __shared__ short lds_a[128 * 64];  // 16 KB
  __shared__ short lds_b[128 * 64];
  const int tid = threadIdx.x, w = tid >> 6, lane = tid & 63;
  const int wr = w >> 1, wc = w & 1;
  const int quad = lane >> 4, lcol = lane & 15;
  const int srow = lane & 15, skq = lane >> 4;
  const int m0 = blockIdx.x * 128, n0 = blockIdx.y * 128;

  f32x4 acc[4][4];
#pragma unroll
  for (int i = 0; i < 4; ++i)
#pragma unroll
    for (int j = 0; j < 4; ++j)
#pragma unroll
      for (int r = 0; r < 4; ++r) acc[i][j][r] = 0.f;

  const short* Abase = xt + (size_t)(m0 + srow) * 512 + skq * 8;
  const short* Bbase = wcat + (size_t)(n0 + srow) * 512 + skq * 8;

  for (int kt = 0; kt < 8; ++kt) {
    const int kb = kt * 64;
    __syncthreads();
#pragma unroll
    for (int gg = 0; gg < 2; ++gg) {
      const int g = w + gg * 4;
      gload_lds16(Abase + (size_t)(g * 16) * 512 + kb,      lds_a + g * 1024);
      gload_lds16(Abase + (size_t)(g * 16) * 512 + kb + 32, lds_a + g * 1024 + 512);
      gload_lds16(Bbase + (size_t)(g * 16) * 512 + kb,      lds_b + g * 1024);
      gload_lds16(Bbase + (size_t)(g * 16) * 512 + kb + 32, lds_b + g * 1024 + 512);
    }
    __syncthreads();
#pragma unroll
    for (int h = 0; h < 2; ++h) {
      bf16x8 af[4], bf[4];
#pragma unroll
      for (int i = 0; i < 4; ++i)
        af[i] = *(const bf16x8*)&lds_a[(wr * 4 + i) * 1024 + h * 512 + lane * 8];
#pragma unroll
      for (int j = 0; j < 4; ++j)
        bf[j] = *(const bf16x8*)&lds_b[(wc * 4 + j) * 1024 + h * 512 + lane * 8];
#pragma unroll
      for (int i = 0; i < 4; ++i)
#pragma unroll
        for (int j = 0; j < 4; ++j)
          acc[i][j] = __builtin_amdgcn_mfma_f32_16x16x32_bf16(af[i], bf[j], acc[i][j], 0, 0, 0);
    }
  }

  const float* bias = (blockIdx.y >= 4) ? bk : bq;
#pragma unroll
  for (int i = 0; i < 4; ++i)
#pragma unroll
    for (int j = 0; j < 4; ++j) {
      const int row = m0 + wr * 64 + i * 16 + quad * 4;
      const int col = n0 + wc * 64 + j * 16 + lcol;
      const float bv = bias[col & 511];
#pragma unroll
      for (int r = 0; r < 4; ++r)
        qk8[(size_t)(row + r) * 1024 + col] = f2e4m3(acc[i][j][r] + bv);
    }
}

// ---------------------------------------------------------------------------
// gemm_scores: q @ k^T (fp8 MFMA), barrier-light restructured K-loop.
// Block tile 128x128; wave w owns rows [m0+w*32, +32) x all 128 cols: acc[2][8].
// A is streamed per-lane straight from global (no LDS, no barrier dependency).
// B staged in LDS in 2 half-K (256 B) stages, frag-ordered:
//   lds_b[j*4096 + kb*1024 + lane*16], j = 16-col group, kb = 64-B k-chunk.
// Per lane 16B = k-quad [quad*16,+16): low 8B -> mfma step .x, high -> .y;
// identical A/B k-permutation => exact dot product (round-2 trick).
// 4 __syncthreads per block (vs 16 in the m97 structure).
__global__ __launch_bounds__(256) void gemm_scores(const unsigned char* __restrict__ qk8,
                                                   float* __restrict__ wsmx) {
  __shared__ unsigned char lds_b[32768];
  const int tid = threadIdx.x, w = tid >> 6, lane = tid & 63;
  const int quad = lane >> 4, lcol = lane & 15;
  const int srow = lane & 15, skb = (lane >> 4) * 16;
  const int m0 = blockIdx.x * 128, n0 = blockIdx.y * 128;

  f32x4 acc[2][8];
#pragma unroll
  for (int rg = 0; rg < 2; ++rg)
#pragma unroll
    for (int j = 0; j < 8; ++j)
#pragma unroll
      for (int r = 0; r < 4; ++r) acc[rg][j][r] = 0.f;

  // A: lane reads its own 16B chunks; row = m0 + w*32 + rg*16 + (lane&15)
  const unsigned char* Abase = qk8 + (size_t)(m0 + w * 32 + srow) * 1024 + skb;
  // B: staging source; row = n0 + j*16 + (lane&15), k cols 512..1023
  const unsigned char* Bbase = qk8 + (size_t)(n0 + srow) * 1024 + 512 + skb;

#pragma unroll
  for (int kh = 0; kh < 2; ++kh) {
    __syncthreads();  // previous half fully consumed before overwrite
#pragma unroll
    for (int jj = 0; jj < 2; ++jj) {
      const int j = w * 2 + jj;
#pragma unroll
      for (int kb = 0; kb < 4; ++kb)
        gload_lds16(Bbase + (size_t)(j * 16) * 1024 + kh * 256 + kb * 64,
                    lds_b + j * 4096 + kb * 1024);
    }
    // prefetch this half's A (8 x 16B) while glds are in flight
    i64x2 af[2][4];
#pragma unroll
    for (int rg = 0; rg < 2; ++rg)
#pragma unroll
      for (int kb = 0; kb < 4; ++kb)
        af[rg][kb] = *(const i64x2*)(Abase + (size_t)rg * 16384 + kh * 256 + kb * 64);
    __syncthreads();  // B half ready
#pragma unroll
    for (int kb = 0; kb < 4; ++kb) {
#pragma unroll
      for (int j = 0; j < 8; ++j) {
        const i64x2 bf = *(const i64x2*)&lds_b[j * 4096 + kb * 1024 + lane * 16];
#pragma unroll
        for (int rg = 0; rg < 2; ++rg) {
          acc[rg][j] = __builtin_amdgcn_mfma_f32_16x16x32_fp8_fp8(
              af[rg][kb].x, bf.x, acc[rg][j], 0, 0, 0);
          acc[rg][j] = __builtin_amdgcn_mfma_f32_16x16x32_fp8_fp8(
              af[rg][kb].y, bf.y, acc[rg][j], 0, 0, 0);
        }
      }
    }
  }

  // per-row max over all 128 cols: wave-local (rows are wave-exclusive)
#pragma unroll
  for (int rg = 0; rg < 2; ++rg) {
#pragma unroll
    for (int r = 0; r < 4; ++r) {
      float v = acc[rg][0][r];
#pragma unroll
      for (int j = 1; j < 8; ++j) v = fmaxf(v, acc[rg][j][r]);
#pragma unroll
      for (int off = 1; off < 16; off <<= 1) v = fmaxf(v, __shfl_xor(v, off));
      if (lcol == 0)
        wsmx[(size_t)blockIdx.y * 8192 + m0 + w * 32 + rg * 16 + quad * 4 + r] = v;
    }
  }
}

// ---------------------------------------------------------------------------
// softmax_xw: logit[m] = scale * mean_img( max over img's 8 col-tiles ); softmax per image
__global__ __launch_bounds__(1024) void softmax_xw(const float* __restrict__ wsmx,
                                                   float* __restrict__ xw) {
  const int b = blockIdx.x, p = threadIdx.x;
  const int m = b * 1024 + p;
  float s = 0.f;
#pragma unroll
  for (int img = 0; img < 8; ++img) {
    float mx = -1e30f;
#pragma unroll
    for (int t = 0; t < 8; ++t) mx = fmaxf(mx, wsmx[(size_t)(img * 8 + t) * 8192 + m]);
    s += mx;
  }
  const float logit = s * 0.005524271728019903f;  // (1/8) * (1/sqrt(512))
  __shared__ float red[16];
  float v = logit;
#pragma unroll
  for (int off = 32; off >= 1; off >>= 1) v = fmaxf(v, __shfl_xor(v, off));
  if ((p & 63) == 0) red[p >> 6] = v;
  __syncthreads();
  float bmax = red[0];
#pragma unroll
  for (int t = 1; t < 16; ++t) bmax = fmaxf(bmax, red[t]);
  const float e = expf(logit - bmax);
  float sv = e;
#pragma unroll
  for (int off = 32; off >= 1; off >>= 1) sv += __shfl_xor(sv, off);
  __syncthreads();
  if ((p & 63) == 0) red[p >> 6] = sv;
  __syncthreads();
  float bsum = 0.f;
#pragma unroll
  for (int t = 0; t < 16; ++t) bsum += red[t];
  xw[m] = e / bsum;
}

// ---------------------------------------------------------------------------
// gemm_out: out[b][co][p] = (xt @ W6^T)[m][co] * xw[m] + b6[co], m = b*1024+p.
// 64x64 tiles, grid (128,8) = 1024 blocks, BK=64 (round-4 structure)
__global__ __launch_bounds__(256) void gemm_out(const short* __restrict__ xt,
                                                const short* __restrict__ wcat,
                                                const float* __restrict__ xw,
                                                const float* __restrict__ b6,
                                                float* __restrict__ out) {
  __shared__ short lds_a[64 * 64];  // 8 KB
  __shared__ short lds_b[64 * 64];
  const int tid = threadIdx.x, w = tid >> 6, lane = tid & 63;
  const int wr = w >> 1, wc = w & 1;
  const int quad = lane >> 4, lcol = lane & 15;
  const int srow = lane & 15, skq = lane >> 4;
  const int m0 = blockIdx.x * 64, n0 = blockIdx.y * 64;

  f32x4 acc[2][2];
#pragma unroll
  for (int i = 0; i < 2; ++i)
#pragma unroll
    for (int j = 0; j < 2; ++j)
#pragma unroll
      for (int r = 0; r < 4; ++r) acc[i][j][r] = 0.f;

  const short* Abase = xt + (size_t)(m0 + w * 16 + srow) * 512 + skq * 8;
  const short* Bbase = wcat + (size_t)(1024 + n0 + w * 16 + srow) * 512 + skq * 8;

  for (int kt = 0; kt < 8; ++kt) {
    const int kb = kt * 64;
    __syncthreads();
    gload_lds16(Abase + kb,      lds_a + w * 1024);
    gload_lds16(Abase + kb + 32, lds_a + w * 1024 + 512);
    gload_lds16(Bbase + kb,      lds_b + w * 1024);
    gload_lds16(Bbase + kb + 32, lds_b + w * 1024 + 512);
    __syncthreads();
#pragma unroll
    for (int h = 0; h < 2; ++h) {
      bf16x8 af[2], bf[2];
#pragma unroll
      for (int i = 0; i < 2; ++i)
        af[i] = *(const bf16x8*)&lds_a[(wr * 2 + i) * 1024 + h * 512 + lane * 8];
#pragma unroll
      for (int j = 0; j < 2; ++j)
        bf[j] = *(const bf16x8*)&lds_b[(wc * 2 + j) * 1024 + h * 512 + lane * 8];
#pragma unroll
      for (int i = 0; i < 2; ++i)
#pragma unroll
        for (int j = 0; j < 2; ++j)
          acc[i][j] = __builtin_amdgcn_mfma_f32_16x16x32_bf16(af[i], bf[j], acc[i][j], 0, 0, 0);
    }
  }

#pragma unroll
  for (int i = 0; i < 2; ++i) {
    const int mbase = m0 + wr * 32 + i * 16 + quad * 4;
    const int b = mbase >> 10, p = mbase & 1023;
    const float4 wv = *(const float4*)&xw[mbase];
#pragma unroll
    for (int j = 0; j < 2; ++j) {
      const int col = n0 + wc * 32 + j * 16 + lcol;
      const float bias = b6[col];
      float4 o;
      o.x = acc[i][j][0] * wv.x + bias;
      o.y = acc[i][j][1] * wv.y + bias;
      o.z = acc[i][j][2] * wv.z + bias;
      o.w = acc[i][j][3] * wv.w + bias;
      *(float4*)&out[((size_t)(b * 512 + col)) * 1024 + p] = o;
    }
  }
}

// ---------------------------------------------------------------------------
extern "C" void kernel_launch(void* const* d_in, const int* in_sizes, int n_in,
                              void* d_out, int out_size, void* d_ws, size_t ws_size,
                              hipStream_t stream) {
  const float* x  = (const float*)d_in[0];
  const float* Wq = (const float*)d_in[1];
  const float* bq = (const float*)d_in[2];
  const float* Wk = (const float*)d_in[3];
  const float* bk = (const float*)d_in[4];
  const float* W6 = (const float*)d_in[5];
  const float* b6 = (const float*)d_in[6];
  float* out = (float*)d_out;

  char* ws = (char*)d_ws;
  short* xt          = (short*)(ws + 0);          //  8 MB  bf16 [8192][512]
  short* wcat        = (short*)(ws + 8388608);    //  1.5MB bf16 [1536][512]
  unsigned char* qk8 = (unsigned char*)(ws + 10485760);  // 8 MB fp8 [8192][1024]
  float* wsmx        = (float*)(ws + 18874368);   //  2 MB  fp32 [64][8192]
  float* xw          = (float*)(ws + 20971520);   // 32 KB  fp32 [8192]

  prep<<<1792, 256, 0, stream>>>(x, Wq, Wk, W6, xt, wcat);
  gemm_qk<<<dim3(64, 8), 256, 0, stream>>>(xt, wcat, bq, bk, qk8);
  gemm_scores<<<dim3(64, 64), 256, 0, stream>>>(qk8, wsmx);
  softmax_xw<<<8, 1024, 0, stream>>>(wsmx, xw);
  gemm_out<<<dim3(128, 8), 256, 0, stream>>>(xt, wcat, xw, b6, out);
}